// Round 6
// baseline (65.643 us; speedup 1.0000x reference)
//
#include <hip/hip_runtime.h>
#include <hip/hip_bf16.h>

typedef __bf16 bf16_t;
typedef __bf16 bf16x8 __attribute__((ext_vector_type(8)));
typedef float  f32x4  __attribute__((ext_vector_type(4)));

#define M_ROWS 12544   // 64*14*14
#define K_DIM  512
#define N_DIM  2048
#define BM 128
#define BN 128
#define BK 32
#define KSTEPS (K_DIM / BK)        // 16
#define TILES_M (M_ROWS / BM)      // 98
#define TILES_N (N_DIM / BN)       // 16
#define NBLK (TILES_M * TILES_N)   // 1568 (divisible by 8)

// ---------------- Kernel 1: residual add + LayerNorm -> bf16 ----------------
__global__ __launch_bounds__(256) void add_ln_bf16(
    const float* __restrict__ xa, const float* __restrict__ xb,
    const float* __restrict__ gamma, const float* __restrict__ beta,
    bf16_t* __restrict__ xn)
{
    const int wave = threadIdx.x >> 6;
    const int lane = threadIdx.x & 63;
    const int row  = blockIdx.x * 4 + wave;
    const size_t base = (size_t)row * K_DIM + lane * 8;

    float4 a0 = *(const float4*)(xa + base);
    float4 a1 = *(const float4*)(xa + base + 4);
    float4 b0 = *(const float4*)(xb + base);
    float4 b1 = *(const float4*)(xb + base + 4);

    float v[8] = {a0.x + b0.x, a0.y + b0.y, a0.z + b0.z, a0.w + b0.w,
                  a1.x + b1.x, a1.y + b1.y, a1.z + b1.z, a1.w + b1.w};
    float s = 0.f, sq = 0.f;
#pragma unroll
    for (int j = 0; j < 8; ++j) { s += v[j]; sq += v[j] * v[j]; }
#pragma unroll
    for (int off = 32; off >= 1; off >>= 1) {
        s  += __shfl_xor(s, off, 64);
        sq += __shfl_xor(sq, off, 64);
    }
    const float mean = s * (1.0f / 512.0f);
    const float var  = sq * (1.0f / 512.0f) - mean * mean;
    const float rstd = rsqrtf(var + 1e-5f);

    float4 g0  = *(const float4*)(gamma + lane * 8);
    float4 g1  = *(const float4*)(gamma + lane * 8 + 4);
    float4 be0 = *(const float4*)(beta  + lane * 8);
    float4 be1 = *(const float4*)(beta  + lane * 8 + 4);
    float g[8]  = {g0.x, g0.y, g0.z, g0.w, g1.x, g1.y, g1.z, g1.w};
    float bt[8] = {be0.x, be0.y, be0.z, be0.w, be1.x, be1.y, be1.z, be1.w};

    bf16x8 o;
#pragma unroll
    for (int j = 0; j < 8; ++j)
        o[j] = (bf16_t)((v[j] - mean) * rstd * g[j] + bt[j]);
    *(bf16x8*)(xn + base) = o;
}

// ---------------- Kernel 2: W [512][2048] f32 -> Wt [2048][512] bf16 --------
__global__ __launch_bounds__(256) void wt_bf16(
    const float* __restrict__ W, bf16_t* __restrict__ Wt)
{
    __shared__ float t[32][33];
    const int bk = blockIdx.x & 15;
    const int bn = blockIdx.x >> 4;
    const int tx = threadIdx.x & 31;
    const int ty = threadIdx.x >> 5;
#pragma unroll
    for (int r = 0; r < 4; ++r) {
        int k = bk * 32 + ty + r * 8;
        t[ty + r * 8][tx] = W[(size_t)k * N_DIM + bn * 32 + tx];
    }
    __syncthreads();
#pragma unroll
    for (int r = 0; r < 4; ++r) {
        int n = bn * 32 + ty + r * 8;
        Wt[(size_t)n * K_DIM + bk * 32 + tx] = (bf16_t)t[tx][ty + r * 8];
    }
}

// ---------------- Kernel 3: bf16 MFMA GEMM + bias + exact GELU --------------
__device__ __forceinline__ void gload_lds16(const bf16_t* g, bf16_t* l) {
    __builtin_amdgcn_global_load_lds(
        (const __attribute__((address_space(1))) void*)g,
        (__attribute__((address_space(3))) void*)l, 16, 0, 0);
}

// Branchless exact-GELU: erf via Abramowitz-Stegun 7.1.26 (|err| < ~2e-7)
__device__ __forceinline__ float gelu_f(float x) {
    const float y = fabsf(x) * 0.70710678118654752f;
    const float t = __builtin_amdgcn_rcpf(__builtin_fmaf(0.3275911f, y, 1.0f));
    float p = __builtin_fmaf(1.061405429f, t, -1.453152027f);
    p = __builtin_fmaf(p, t, 1.421413741f);
    p = __builtin_fmaf(p, t, -0.284496736f);
    p = __builtin_fmaf(p, t, 0.254829592f);
    p = p * t;
    const float e = __expf(-y * y);
    float er = __builtin_fmaf(-p, e, 1.0f);   // erf(|x|/sqrt2)
    er = __builtin_copysignf(er, x);
    return 0.5f * x * (1.0f + er);
}

// BK=32: row = 64 B = 4 x 16B chunks. Swizzle slot = chunk ^ ((row>>1)&3)
// spreads a j-group's 16 rows uniformly (2 rows per 16B bank-quad slot =
// b128 minimum aliasing). Applied BOTH sides (rule #21): inverse-permuted
// per-lane global source (gload_lds writes linearly), forward on ds_read.
__global__ __launch_bounds__(256, 4) void gemm_bias_gelu(
    const bf16_t* __restrict__ A,   // [M_ROWS][K_DIM] bf16
    const bf16_t* __restrict__ Bt,  // [N_DIM][K_DIM]  bf16 (W^T)
    const float* __restrict__ bias, // [N_DIM]
    float* __restrict__ out)        // [M_ROWS][N_DIM] f32
{
    __shared__ bf16_t As[2][BM * BK];   // 2 x 8 KB
    __shared__ bf16_t Bs[2][BN * BK];   // 2 x 8 KB  -> 32 KB total

    // XCD-chunked bijective swizzle (1568 % 8 == 0), tn-fast: 16 consecutive
    // wgs share one A-panel and sweep all of B (2 MB bf16) -> L2-fit.
    const int bid = blockIdx.x;
    const int wg  = (bid & 7) * (NBLK / 8) + (bid >> 3);
    const int tm  = wg >> 4;
    const int tn  = wg & 15;

    const int tid  = threadIdx.x;
    const int wave = tid >> 6;
    const int lane = tid & 63;
    const int wr = wave >> 1;
    const int wc = wave & 1;

    const bf16_t* Ab = A  + (size_t)tm * BM * K_DIM;
    const bf16_t* Bb = Bt + (size_t)tn * BN * K_DIM;

    // staging: seg = 16 rows x 32 k = 1024 B = 64 lanes x 16 B
    const int srow = lane >> 2;                       // row within segment
    const int gsrc = (lane & 3) ^ ((lane >> 3) & 3);  // inverse-swizzled chunk

    f32x4 acc[4][4];
#pragma unroll
    for (int m = 0; m < 4; ++m)
#pragma unroll
        for (int n = 0; n < 4; ++n)
            acc[m][n] = (f32x4){0.f, 0.f, 0.f, 0.f};

    auto stage = [&](int buf, int k0) {
#pragma unroll
        for (int c = 0; c < 2; ++c) {
            const int seg = wave * 2 + c;             // wave-uniform LDS base
            const int row = seg * 16 + srow;
            gload_lds16(Ab + (size_t)row * K_DIM + k0 + gsrc * 8, &As[buf][seg * 512]);
            gload_lds16(Bb + (size_t)row * K_DIM + k0 + gsrc * 8, &Bs[buf][seg * 512]);
        }
    };

    stage(0, 0);   // prologue: 4 loads in flight

#pragma unroll
    for (int t = 0; t < KSTEPS; ++t) {
        const int cur = t & 1;
        if (t < KSTEPS - 1) {
            stage(cur ^ 1, (t + 1) * BK);                    // +4 loads (next tile)
            asm volatile("s_waitcnt vmcnt(4)" ::: "memory"); // tile t landed; next in flight
        } else {
            asm volatile("s_waitcnt vmcnt(0)" ::: "memory");
        }
        __builtin_amdgcn_s_barrier();

        bf16x8 af[4], bfr[4];
        const int j = lane >> 4;                      // 16B k-chunk 0..3
#pragma unroll
        for (int m = 0; m < 4; ++m) {
            const int r = wr * 64 + m * 16 + (lane & 15);
            af[m] = *(const bf16x8*)(&As[cur][r * BK + ((j ^ ((r >> 1) & 3)) << 3)]);
        }
#pragma unroll
        for (int n = 0; n < 4; ++n) {
            const int r = wc * 64 + n * 16 + (lane & 15);
            bfr[n] = *(const bf16x8*)(&Bs[cur][r * BK + ((j ^ ((r >> 1) & 3)) << 3)]);
        }
        __builtin_amdgcn_s_setprio(1);
#pragma unroll
        for (int m = 0; m < 4; ++m)
#pragma unroll
            for (int n = 0; n < 4; ++n)
                acc[m][n] = __builtin_amdgcn_mfma_f32_16x16x32_bf16(
                    af[m], bfr[n], acc[m][n], 0, 0, 0);
        __builtin_amdgcn_s_setprio(0);

        if (t < KSTEPS - 1) __builtin_amdgcn_s_barrier();  // reads done before restage
    }

    // Epilogue: bias + exact GELU, nontemporal stores.
    // C/D layout: col = lane&15, row = (lane>>4)*4 + reg.
    const int rbase = tm * BM + wr * 64;
    const int cbase = tn * BN + wc * 64;
#pragma unroll
    for (int n = 0; n < 4; ++n) {
        const int col = cbase + n * 16 + (lane & 15);
        const float bv = bias[col];
#pragma unroll
        for (int m = 0; m < 4; ++m) {
            const int row0 = rbase + m * 16 + (lane >> 4) * 4;
#pragma unroll
            for (int i = 0; i < 4; ++i) {
                const float x = acc[m][n][i] + bv;
                __builtin_nontemporal_store(gelu_f(x),
                    out + (size_t)(row0 + i) * N_DIM + col);
            }
        }
    }
}

extern "C" void kernel_launch(void* const* d_in, const int* in_sizes, int n_in,
                              void* d_out, int out_size, void* d_ws, size_t ws_size,
                              hipStream_t stream)
{
    const float* x203  = (const float*)d_in[0];
    const float* x217  = (const float*)d_in[1];
    const float* gamma = (const float*)d_in[2];
    const float* beta  = (const float*)d_in[3];
    const float* W     = (const float*)d_in[4];
    const float* bias  = (const float*)d_in[5];
    float* out = (float*)d_out;

    bf16_t* xn = (bf16_t*)d_ws;
    bf16_t* Wt = (bf16_t*)((char*)d_ws + (size_t)M_ROWS * K_DIM * sizeof(bf16_t));

    add_ln_bf16<<<M_ROWS / 4, 256, 0, stream>>>(x203, x217, gamma, beta, xn);
    wt_bf16<<<(K_DIM / 32) * (N_DIM / 32), 256, 0, stream>>>(W, Wt);
    gemm_bias_gelu<<<NBLK, 256, 0, stream>>>(xn, Wt, bias, out);
}

// Round 7
// 63.447 us; speedup vs baseline: 1.0346x; 1.0346x over previous
//
#include <hip/hip_runtime.h>
#include <hip/hip_bf16.h>

typedef __bf16 bf16_t;
typedef __bf16 bf16x8 __attribute__((ext_vector_type(8)));
typedef float  f32x4  __attribute__((ext_vector_type(4)));

#define M_ROWS 12544   // 64*14*14
#define K_DIM  512
#define N_DIM  2048
#define BM 256
#define BN 256
#define BK 64
#define KSTEPS (K_DIM / BK)        // 8
#define TILES_M (M_ROWS / BM)      // 49
#define TILES_N (N_DIM / BN)       // 8
#define NBLK (TILES_M * TILES_N)   // 392 (divisible by 8)

// ---------------- Kernel 1: residual add + LayerNorm -> bf16 ----------------
__global__ __launch_bounds__(256) void add_ln_bf16(
    const float* __restrict__ xa, const float* __restrict__ xb,
    const float* __restrict__ gamma, const float* __restrict__ beta,
    bf16_t* __restrict__ xn)
{
    const int wave = threadIdx.x >> 6;
    const int lane = threadIdx.x & 63;
    const int row  = blockIdx.x * 4 + wave;
    const size_t base = (size_t)row * K_DIM + lane * 8;

    float4 a0 = *(const float4*)(xa + base);
    float4 a1 = *(const float4*)(xa + base + 4);
    float4 b0 = *(const float4*)(xb + base);
    float4 b1 = *(const float4*)(xb + base + 4);

    float v[8] = {a0.x + b0.x, a0.y + b0.y, a0.z + b0.z, a0.w + b0.w,
                  a1.x + b1.x, a1.y + b1.y, a1.z + b1.z, a1.w + b1.w};
    float s = 0.f, sq = 0.f;
#pragma unroll
    for (int j = 0; j < 8; ++j) { s += v[j]; sq += v[j] * v[j]; }
#pragma unroll
    for (int off = 32; off >= 1; off >>= 1) {
        s  += __shfl_xor(s, off, 64);
        sq += __shfl_xor(sq, off, 64);
    }
    const float mean = s * (1.0f / 512.0f);
    const float var  = sq * (1.0f / 512.0f) - mean * mean;
    const float rstd = rsqrtf(var + 1e-5f);

    float4 g0  = *(const float4*)(gamma + lane * 8);
    float4 g1  = *(const float4*)(gamma + lane * 8 + 4);
    float4 be0 = *(const float4*)(beta  + lane * 8);
    float4 be1 = *(const float4*)(beta  + lane * 8 + 4);
    float g[8]  = {g0.x, g0.y, g0.z, g0.w, g1.x, g1.y, g1.z, g1.w};
    float bt[8] = {be0.x, be0.y, be0.z, be0.w, be1.x, be1.y, be1.z, be1.w};

    bf16x8 o;
#pragma unroll
    for (int j = 0; j < 8; ++j)
        o[j] = (bf16_t)((v[j] - mean) * rstd * g[j] + bt[j]);
    *(bf16x8*)(xn + base) = o;
}

// ---------------- Kernel 2: W [512][2048] f32 -> Wt [2048][512] bf16 --------
__global__ __launch_bounds__(256) void wt_bf16(
    const float* __restrict__ W, bf16_t* __restrict__ Wt)
{
    __shared__ float t[32][33];
    const int bk = blockIdx.x & 15;
    const int bn = blockIdx.x >> 4;
    const int tx = threadIdx.x & 31;
    const int ty = threadIdx.x >> 5;
#pragma unroll
    for (int r = 0; r < 4; ++r) {
        int k = bk * 32 + ty + r * 8;
        t[ty + r * 8][tx] = W[(size_t)k * N_DIM + bn * 32 + tx];
    }
    __syncthreads();
#pragma unroll
    for (int r = 0; r < 4; ++r) {
        int n = bn * 32 + ty + r * 8;
        Wt[(size_t)n * K_DIM + bk * 32 + tx] = (bf16_t)t[tx][ty + r * 8];
    }
}

// ---------------- Kernel 3: bf16 MFMA GEMM + bias + exact GELU --------------
__device__ __forceinline__ void gload_lds16(const bf16_t* g, bf16_t* l) {
    __builtin_amdgcn_global_load_lds(
        (const __attribute__((address_space(1))) void*)g,
        (__attribute__((address_space(3))) void*)l, 16, 0, 0);
}

// Branchless exact-GELU: erf via Abramowitz-Stegun 7.1.26 (|err| < ~2e-7)
__device__ __forceinline__ float gelu_f(float x) {
    const float y = fabsf(x) * 0.70710678118654752f;
    const float t = __builtin_amdgcn_rcpf(__builtin_fmaf(0.3275911f, y, 1.0f));
    float p = __builtin_fmaf(1.061405429f, t, -1.453152027f);
    p = __builtin_fmaf(p, t, 1.421413741f);
    p = __builtin_fmaf(p, t, -0.284496736f);
    p = __builtin_fmaf(p, t, 0.254829592f);
    p = p * t;
    const float e = __expf(-y * y);
    float er = __builtin_fmaf(-p, e, 1.0f);   // erf(|x|/sqrt2)
    er = __builtin_copysignf(er, x);
    return 0.5f * x * (1.0f + er);
}

// 256x256 tile, 8 waves (2M x 4N), BK=64, double-buffered (128 KB LDS).
// Per wave-step: 24 ds_read_b128 per 64 MFMA. XOR swizzle: row = 8 x 16B
// chunks; swizzled slot = chunk ^ (row&7), applied BOTH sides (rule #21):
// inverse on the per-lane global source (gload_lds writes LDS linearly),
// forward on ds_read.
__global__ __launch_bounds__(512) void gemm_bias_gelu(
    const bf16_t* __restrict__ A,   // [M_ROWS][K_DIM] bf16
    const bf16_t* __restrict__ Bt,  // [N_DIM][K_DIM]  bf16 (W^T)
    const float* __restrict__ bias, // [N_DIM]
    float* __restrict__ out)        // [M_ROWS][N_DIM] f32
{
    __shared__ bf16_t As[2][BM * BK];   // 2 x 32 KB
    __shared__ bf16_t Bs[2][BN * BK];   // 2 x 32 KB  -> 128 KB total

    // XCD-chunked bijective swizzle (392 % 8 == 0), tn-fast: 8 consecutive
    // wgs share one 256-row A-panel and sweep all of B (2 MB) -> L2-fit.
    const int bid = blockIdx.x;
    const int wg  = (bid & 7) * (NBLK / 8) + (bid >> 3);
    const int tm  = wg >> 3;            // 0..48
    const int tn  = wg & 7;             // 0..7

    const int tid  = threadIdx.x;
    const int wave = tid >> 6;          // 0..7
    const int lane = tid & 63;
    const int wr = wave >> 2;           // 0..1  (M half)
    const int wc = wave & 3;            // 0..3  (N quarter)

    const bf16_t* Ab = A  + (size_t)tm * BM * K_DIM;
    const bf16_t* Bb = Bt + (size_t)tn * BN * K_DIM;

    // staging: seg = 8 rows x 64 k = 1024 B = 64 lanes x 16 B
    const int srow = lane >> 3;                 // 0..7 row within segment
    const int jsrc = (lane & 7) ^ srow;         // inverse-swizzled 16B chunk

    f32x4 acc[8][4];
#pragma unroll
    for (int m = 0; m < 8; ++m)
#pragma unroll
        for (int n = 0; n < 4; ++n)
            acc[m][n] = (f32x4){0.f, 0.f, 0.f, 0.f};

    auto stage = [&](int buf, int k0) {
#pragma unroll
        for (int c = 0; c < 4; ++c) {
            const int seg = wave * 4 + c;       // 0..31, wave-uniform LDS base
            const int row = seg * 8 + srow;
            gload_lds16(Ab + (size_t)row * K_DIM + k0 + jsrc * 8, &As[buf][seg * 512]);
            gload_lds16(Bb + (size_t)row * K_DIM + k0 + jsrc * 8, &Bs[buf][seg * 512]);
        }
    };

    auto compute = [&](int cur) {
#pragma unroll
        for (int kk = 0; kk < 2; ++kk) {
            bf16x8 af[8], bfr[4];
            const int j = kk * 4 + (lane >> 4);   // 16B k-chunk 0..7
#pragma unroll
            for (int m = 0; m < 8; ++m) {
                const int r = wr * 128 + m * 16 + (lane & 15);
                af[m] = *(const bf16x8*)(&As[cur][r * BK + ((j ^ (r & 7)) << 3)]);
            }
#pragma unroll
            for (int n = 0; n < 4; ++n) {
                const int r = wc * 64 + n * 16 + (lane & 15);
                bfr[n] = *(const bf16x8*)(&Bs[cur][r * BK + ((j ^ (r & 7)) << 3)]);
            }
#pragma unroll
            for (int m = 0; m < 8; ++m)
#pragma unroll
                for (int n = 0; n < 4; ++n)
                    acc[m][n] = __builtin_amdgcn_mfma_f32_16x16x32_bf16(
                        af[m], bfr[n], acc[m][n], 0, 0, 0);
        }
    };

    stage(0, 0);   // prologue: 8 loads/wave in flight

    for (int t = 0; t < KSTEPS - 1; ++t) {
        stage((t + 1) & 1, (t + 1) * BK);                // +8 -> 16 outstanding
        asm volatile("s_waitcnt vmcnt(8)" ::: "memory"); // tile t landed; t+1 in flight
        __builtin_amdgcn_s_barrier();
        compute(t & 1);
        __builtin_amdgcn_s_barrier();                    // reads done before restage
    }
    asm volatile("s_waitcnt vmcnt(0)" ::: "memory");
    __builtin_amdgcn_s_barrier();
    compute((KSTEPS - 1) & 1);

    // Epilogue: bias + exact GELU, nontemporal stores.
    // C/D layout: col = lane&15, row = (lane>>4)*4 + reg.
    const int rbase = tm * BM + wr * 128;
    const int cbase = tn * BN + wc * 64;
#pragma unroll
    for (int n = 0; n < 4; ++n) {
        const int col = cbase + n * 16 + (lane & 15);
        const float bv = bias[col];
#pragma unroll
        for (int m = 0; m < 8; ++m) {
            const int row0 = rbase + m * 16 + (lane >> 4) * 4;
#pragma unroll
            for (int i = 0; i < 4; ++i) {
                const float x = acc[m][n][i] + bv;
                __builtin_nontemporal_store(gelu_f(x),
                    out + (size_t)(row0 + i) * N_DIM + col);
            }
        }
    }
}

extern "C" void kernel_launch(void* const* d_in, const int* in_sizes, int n_in,
                              void* d_out, int out_size, void* d_ws, size_t ws_size,
                              hipStream_t stream)
{
    const float* x203  = (const float*)d_in[0];
    const float* x217  = (const float*)d_in[1];
    const float* gamma = (const float*)d_in[2];
    const float* beta  = (const float*)d_in[3];
    const float* W     = (const float*)d_in[4];
    const float* bias  = (const float*)d_in[5];
    float* out = (float*)d_out;

    bf16_t* xn = (bf16_t*)d_ws;
    bf16_t* Wt = (bf16_t*)((char*)d_ws + (size_t)M_ROWS * K_DIM * sizeof(bf16_t));

    add_ln_bf16<<<M_ROWS / 4, 256, 0, stream>>>(x203, x217, gamma, beta, xn);
    wt_bf16<<<(K_DIM / 32) * (N_DIM / 32), 256, 0, stream>>>(W, Wt);
    gemm_bias_gelu<<<NBLK, 512, 0, stream>>>(xn, Wt, bias, out);
}